// Round 4
// baseline (270.859 us; speedup 1.0000x reference)
//
#include <hip/hip_runtime.h>
#include <hip/hip_fp16.h>

#define N_NODES 500000
#define N_CELLS 1000000
#define N_PTS   8000000

typedef float f32x4 __attribute__((ext_vector_type(4)));
typedef float f32x2 __attribute__((ext_vector_type(2)));
typedef int   i32x4 __attribute__((ext_vector_type(4)));

// ---------------- Pass 1: gather per-cell nodal values into f16 rows ----------------
// cellvals[c] = 16 halves (32B, aligned): h2[k] = (v0(nk), v1(nk)) for k=0..5, pad h2[6..7]=0
__global__ __launch_bounds__(256) void gather_cellvals_f16_kernel(
    const float* __restrict__ nodal,   // (2, N_NODES)
    const int*   __restrict__ conn,    // (N_CELLS, 6), 1-based
    __half*      __restrict__ cellvals)// (N_CELLS, 16) halves
{
    const int t  = blockIdx.x * blockDim.x + threadIdx.x;
    const int c0 = t * 2;
    if (c0 >= N_CELLS) return;

    // two cells: 12 ints = 3 x int4 (48B stride, 16B aligned since c0 even)
    const i32x4* cp = reinterpret_cast<const i32x4*>(conn + (size_t)c0 * 6);
    const i32x4 i0 = cp[0], i1 = cp[1], i2 = cp[2];
    const int n[12] = { i0.x, i0.y, i0.z, i0.w, i1.x, i1.y,
                        i1.z, i1.w, i2.x, i2.y, i2.z, i2.w };

    union Row { __half2 h2[8]; f32x4 f4[2]; };

    #pragma unroll
    for (int cc = 0; cc < 2; ++cc) {
        Row r;
        #pragma unroll
        for (int k = 0; k < 6; ++k) {
            const int node = n[cc * 6 + k] - 1;
            r.h2[k] = __floats2half2_rn(nodal[node], nodal[N_NODES + node]);
        }
        r.h2[6] = __floats2half2_rn(0.f, 0.f);
        r.h2[7] = __floats2half2_rn(0.f, 0.f);
        f32x4* dst = reinterpret_cast<f32x4*>(cellvals + (size_t)(c0 + cc) * 16);
        dst[0] = r.f4[0];
        dst[1] = r.f4[1];
    }
}

// ---------------- Pass 2: per-point interpolation (4 points/thread) ----------------
__global__ __launch_bounds__(256) void interp2d_f16_kernel(
    const __half* __restrict__ cellvals, // (N_CELLS, 16) halves
    const float*  __restrict__ sf,       // (N_PTS, 6)
    const int*    __restrict__ cid,      // (N_PTS,)
    float* __restrict__ out)             // (2, N_PTS)
{
    const int t  = blockIdx.x * blockDim.x + threadIdx.x;
    const int p0 = t * 4;
    if (p0 >= N_PTS) return;

    const i32x4 c = __builtin_nontemporal_load(reinterpret_cast<const i32x4*>(cid + p0));
    const int cells[4] = { c.x, c.y, c.z, c.w };

    // 24 shape-function floats: 6 x float4, nontemporal (streamed once)
    const f32x4* sfp = reinterpret_cast<const f32x4*>(sf + (size_t)p0 * 6);
    float w[24];
    #pragma unroll
    for (int j = 0; j < 6; ++j) {
        const f32x4 s = __builtin_nontemporal_load(sfp + j);
        w[4 * j + 0] = s.x; w[4 * j + 1] = s.y; w[4 * j + 2] = s.z; w[4 * j + 3] = s.w;
    }

    // issue all random row loads up front (each row: one 16B + one 8B in same 64B sector)
    union RowA { f32x4 f; __half2 h2[4]; };
    union RowB { f32x2 f; __half2 h2[2]; };
    RowA ra[4]; RowB rb[4];
    #pragma unroll
    for (int i = 0; i < 4; ++i) {
        const __half* row = cellvals + (size_t)cells[i] * 16;
        ra[i].f = *reinterpret_cast<const f32x4*>(row);
        rb[i].f = *reinterpret_cast<const f32x2*>(row + 8);
    }

    float o0[4], o1[4];
    #pragma unroll
    for (int i = 0; i < 4; ++i) {
        float a0 = 0.f, a1 = 0.f;
        #pragma unroll
        for (int k = 0; k < 6; ++k) {
            const float2 v = __half22float2(k < 4 ? ra[i].h2[k] : rb[i].h2[k - 4]);
            const float wk = w[i * 6 + k];
            a0 = fmaf(wk, v.x, a0);
            a1 = fmaf(wk, v.y, a1);
        }
        o0[i] = a0; o1[i] = a1;
    }

    f32x4 v0; v0.x = o0[0]; v0.y = o0[1]; v0.z = o0[2]; v0.w = o0[3];
    f32x4 v1; v1.x = o1[0]; v1.y = o1[1]; v1.z = o1[2]; v1.w = o1[3];
    __builtin_nontemporal_store(v0, reinterpret_cast<f32x4*>(out + p0));
    __builtin_nontemporal_store(v1, reinterpret_cast<f32x4*>(out + N_PTS + p0));
}

// ---------------- Fallback (round-1 direct kernel) ----------------
__global__ __launch_bounds__(256) void interp2d_direct_kernel(
    const float* __restrict__ nodal,
    const float* __restrict__ sf,
    const int*   __restrict__ conn,
    const int*   __restrict__ cid,
    float* __restrict__ out)
{
    const int t  = blockIdx.x * blockDim.x + threadIdx.x;
    const int p0 = t * 2;
    if (p0 >= N_PTS) return;

    const int2 c = *reinterpret_cast<const int2*>(cid + p0);
    const float4* sfp = reinterpret_cast<const float4*>(sf + (size_t)p0 * 6);
    const float4 s0 = sfp[0];
    const float4 s1 = sfp[1];
    const float4 s2 = sfp[2];
    const float w0[6] = { s0.x, s0.y, s0.z, s0.w, s1.x, s1.y };
    const float w1[6] = { s1.z, s1.w, s2.x, s2.y, s2.z, s2.w };

    float o00 = 0.f, o01 = 0.f, o10 = 0.f, o11 = 0.f;
    {
        const int* cr = conn + (size_t)c.x * 6;
        #pragma unroll
        for (int k = 0; k < 6; ++k) {
            const int node = cr[k] - 1;
            o00 = fmaf(w0[k], nodal[node], o00);
            o01 = fmaf(w0[k], nodal[N_NODES + node], o01);
        }
    }
    {
        const int* cr = conn + (size_t)c.y * 6;
        #pragma unroll
        for (int k = 0; k < 6; ++k) {
            const int node = cr[k] - 1;
            o10 = fmaf(w1[k], nodal[node], o10);
            o11 = fmaf(w1[k], nodal[N_NODES + node], o11);
        }
    }
    *reinterpret_cast<float2*>(out + p0)         = make_float2(o00, o10);
    *reinterpret_cast<float2*>(out + N_PTS + p0) = make_float2(o01, o11);
}

extern "C" void kernel_launch(void* const* d_in, const int* in_sizes, int n_in,
                              void* d_out, int out_size, void* d_ws, size_t ws_size,
                              hipStream_t stream) {
    const float* nodal = (const float*)d_in[0];  // (2, N_NODES)
    const float* sf    = (const float*)d_in[1];  // (N_PTS, 6)
    const int*   conn  = (const int*)d_in[2];    // (N_CELLS, 6)
    const int*   cid   = (const int*)d_in[3];    // (N_PTS,)
    float* out = (float*)d_out;                  // (2, N_PTS)

    const size_t cellvals_bytes = (size_t)N_CELLS * 16 * sizeof(__half); // 32 MB

    if (ws_size >= cellvals_bytes) {
        __half* cellvals = (__half*)d_ws;
        {
            const int threads = 256;
            const int blocks = (N_CELLS / 2 + threads - 1) / threads;
            gather_cellvals_f16_kernel<<<blocks, threads, 0, stream>>>(nodal, conn, cellvals);
        }
        {
            const int threads = 256;
            const int blocks = (N_PTS / 4 + threads - 1) / threads;
            interp2d_f16_kernel<<<blocks, threads, 0, stream>>>(cellvals, sf, cid, out);
        }
    } else {
        const int threads = 256;
        const int blocks = (N_PTS / 2 + threads - 1) / threads;
        interp2d_direct_kernel<<<blocks, threads, 0, stream>>>(nodal, sf, conn, cid, out);
    }
}

// Round 5
// 232.673 us; speedup vs baseline: 1.1641x; 1.1641x over previous
//
#include <hip/hip_runtime.h>
#include <hip/hip_fp16.h>

#define N_NODES 500000
#define N_CELLS 1000000
#define N_PTS   8000000

typedef float f32x4 __attribute__((ext_vector_type(4)));
typedef float f32x2 __attribute__((ext_vector_type(2)));

// ---------------- Pass 0: pack nodal (2,N) f32 -> interleaved half2 table (2 MB) ----------------
__global__ __launch_bounds__(256) void pack_nodal_h2_kernel(
    const float* __restrict__ nodal,   // (2, N_NODES)
    __half2*     __restrict__ nodal_h2)// (N_NODES,)
{
    const int n0 = (blockIdx.x * blockDim.x + threadIdx.x) * 4;
    if (n0 >= N_NODES) return;
    // N_NODES = 500000 divisible by 4 -> no partial tail
    const f32x4 a = *reinterpret_cast<const f32x4*>(nodal + n0);
    const f32x4 b = *reinterpret_cast<const f32x4*>(nodal + N_NODES + n0);
    __half2 h[4];
    h[0] = __floats2half2_rn(a.x, b.x);
    h[1] = __floats2half2_rn(a.y, b.y);
    h[2] = __floats2half2_rn(a.z, b.z);
    h[3] = __floats2half2_rn(a.w, b.w);
    *reinterpret_cast<f32x4*>(nodal_h2 + n0) = *reinterpret_cast<f32x4*>(h);
}

// ---------------- Pass 1: gather per-cell nodal values into f16 rows ----------------
// cellvals[c] = 16 halves (32B, aligned): h2[k] = (v0(nk), v1(nk)) for k=0..5, pad = 0
__global__ __launch_bounds__(256) void gather_cellvals_f16_kernel(
    const __half2* __restrict__ nodal_h2, // (N_NODES,) interleaved (v0,v1)
    const int*     __restrict__ conn,     // (N_CELLS, 6), 1-based
    __half*        __restrict__ cellvals) // (N_CELLS, 16) halves
{
    const int t  = blockIdx.x * blockDim.x + threadIdx.x;
    const int c0 = t * 2;
    if (c0 >= N_CELLS) return;

    // two cells: 12 ints = 3 x int4 (48B stride, 16B aligned since c0 even)
    const int4* cp = reinterpret_cast<const int4*>(conn + (size_t)c0 * 6);
    const int4 i0 = cp[0], i1 = cp[1], i2 = cp[2];
    const int n[12] = { i0.x, i0.y, i0.z, i0.w, i1.x, i1.y,
                        i1.z, i1.w, i2.x, i2.y, i2.z, i2.w };

    union Row { __half2 h2[8]; f32x4 f4[2]; };

    #pragma unroll
    for (int cc = 0; cc < 2; ++cc) {
        Row r;
        #pragma unroll
        for (int k = 0; k < 6; ++k) {
            r.h2[k] = nodal_h2[n[cc * 6 + k] - 1];  // 4B gather, 2MB L2-resident table
        }
        r.h2[6] = __floats2half2_rn(0.f, 0.f);
        r.h2[7] = __floats2half2_rn(0.f, 0.f);
        f32x4* dst = reinterpret_cast<f32x4*>(cellvals + (size_t)(c0 + cc) * 16);
        dst[0] = r.f4[0];
        dst[1] = r.f4[1];
    }
}

// ---------------- Pass 2: per-point interpolation (4 points/thread) ----------------
__global__ __launch_bounds__(256) void interp2d_f16_kernel(
    const __half* __restrict__ cellvals, // (N_CELLS, 16) halves
    const float*  __restrict__ sf,       // (N_PTS, 6)
    const int*    __restrict__ cid,      // (N_PTS,)
    float* __restrict__ out)             // (2, N_PTS)
{
    const int t  = blockIdx.x * blockDim.x + threadIdx.x;
    const int p0 = t * 4;
    if (p0 >= N_PTS) return;

    const int4 c = *reinterpret_cast<const int4*>(cid + p0);
    const int cells[4] = { c.x, c.y, c.z, c.w };

    // 24 shape-function floats: 6 x float4 (regular loads — lines shared across instrs)
    const float4* sfp = reinterpret_cast<const float4*>(sf + (size_t)p0 * 6);
    float w[24];
    #pragma unroll
    for (int j = 0; j < 6; ++j) {
        const float4 s = sfp[j];
        w[4 * j + 0] = s.x; w[4 * j + 1] = s.y; w[4 * j + 2] = s.z; w[4 * j + 3] = s.w;
    }

    // issue all random row loads up front (each row: one 16B + one 8B in same 64B line)
    union RowA { f32x4 f; __half2 h2[4]; };
    union RowB { f32x2 f; __half2 h2[2]; };
    RowA ra[4]; RowB rb[4];
    #pragma unroll
    for (int i = 0; i < 4; ++i) {
        const __half* row = cellvals + (size_t)cells[i] * 16;
        ra[i].f = *reinterpret_cast<const f32x4*>(row);
        rb[i].f = *reinterpret_cast<const f32x2*>(row + 8);
    }

    float o0[4], o1[4];
    #pragma unroll
    for (int i = 0; i < 4; ++i) {
        float a0 = 0.f, a1 = 0.f;
        #pragma unroll
        for (int k = 0; k < 6; ++k) {
            const float2 v = __half22float2(k < 4 ? ra[i].h2[k] : rb[i].h2[k - 4]);
            const float wk = w[i * 6 + k];
            a0 = fmaf(wk, v.x, a0);
            a1 = fmaf(wk, v.y, a1);
        }
        o0[i] = a0; o1[i] = a1;
    }

    // NT stores: write-once full lines, keep them out of L2
    f32x4 v0; v0.x = o0[0]; v0.y = o0[1]; v0.z = o0[2]; v0.w = o0[3];
    f32x4 v1; v1.x = o1[0]; v1.y = o1[1]; v1.z = o1[2]; v1.w = o1[3];
    __builtin_nontemporal_store(v0, reinterpret_cast<f32x4*>(out + p0));
    __builtin_nontemporal_store(v1, reinterpret_cast<f32x4*>(out + N_PTS + p0));
}

// ---------------- Fallback (round-1 direct kernel) ----------------
__global__ __launch_bounds__(256) void interp2d_direct_kernel(
    const float* __restrict__ nodal,
    const float* __restrict__ sf,
    const int*   __restrict__ conn,
    const int*   __restrict__ cid,
    float* __restrict__ out)
{
    const int t  = blockIdx.x * blockDim.x + threadIdx.x;
    const int p0 = t * 2;
    if (p0 >= N_PTS) return;

    const int2 c = *reinterpret_cast<const int2*>(cid + p0);
    const float4* sfp = reinterpret_cast<const float4*>(sf + (size_t)p0 * 6);
    const float4 s0 = sfp[0];
    const float4 s1 = sfp[1];
    const float4 s2 = sfp[2];
    const float w0[6] = { s0.x, s0.y, s0.z, s0.w, s1.x, s1.y };
    const float w1[6] = { s1.z, s1.w, s2.x, s2.y, s2.z, s2.w };

    float o00 = 0.f, o01 = 0.f, o10 = 0.f, o11 = 0.f;
    {
        const int* cr = conn + (size_t)c.x * 6;
        #pragma unroll
        for (int k = 0; k < 6; ++k) {
            const int node = cr[k] - 1;
            o00 = fmaf(w0[k], nodal[node], o00);
            o01 = fmaf(w0[k], nodal[N_NODES + node], o01);
        }
    }
    {
        const int* cr = conn + (size_t)c.y * 6;
        #pragma unroll
        for (int k = 0; k < 6; ++k) {
            const int node = cr[k] - 1;
            o10 = fmaf(w1[k], nodal[node], o10);
            o11 = fmaf(w1[k], nodal[N_NODES + node], o11);
        }
    }
    *reinterpret_cast<float2*>(out + p0)         = make_float2(o00, o10);
    *reinterpret_cast<float2*>(out + N_PTS + p0) = make_float2(o01, o11);
}

extern "C" void kernel_launch(void* const* d_in, const int* in_sizes, int n_in,
                              void* d_out, int out_size, void* d_ws, size_t ws_size,
                              hipStream_t stream) {
    const float* nodal = (const float*)d_in[0];  // (2, N_NODES)
    const float* sf    = (const float*)d_in[1];  // (N_PTS, 6)
    const int*   conn  = (const int*)d_in[2];    // (N_CELLS, 6)
    const int*   cid   = (const int*)d_in[3];    // (N_PTS,)
    float* out = (float*)d_out;                  // (2, N_PTS)

    const size_t cellvals_bytes = (size_t)N_CELLS * 16 * sizeof(__half);   // 32 MB
    const size_t nodal_h2_bytes = (size_t)N_NODES * sizeof(__half2);       // 2 MB

    if (ws_size >= cellvals_bytes + nodal_h2_bytes) {
        __half*  cellvals = (__half*)d_ws;
        __half2* nodal_h2 = (__half2*)((char*)d_ws + cellvals_bytes);
        {
            const int threads = 256;
            const int blocks = (N_NODES / 4 + threads - 1) / threads;
            pack_nodal_h2_kernel<<<blocks, threads, 0, stream>>>(nodal, nodal_h2);
        }
        {
            const int threads = 256;
            const int blocks = (N_CELLS / 2 + threads - 1) / threads;
            gather_cellvals_f16_kernel<<<blocks, threads, 0, stream>>>(nodal_h2, conn, cellvals);
        }
        {
            const int threads = 256;
            const int blocks = (N_PTS / 4 + threads - 1) / threads;
            interp2d_f16_kernel<<<blocks, threads, 0, stream>>>(cellvals, sf, cid, out);
        }
    } else {
        const int threads = 256;
        const int blocks = (N_PTS / 2 + threads - 1) / threads;
        interp2d_direct_kernel<<<blocks, threads, 0, stream>>>(nodal, sf, conn, cid, out);
    }
}